// Round 8
// baseline (270.468 us; speedup 1.0000x reference)
//
#include <hip/hip_runtime.h>
#include <hip/hip_bf16.h>
#include <hip/hip_fp16.h>

#define BS 256
#define BS3 256          // csr kernel block size
#define NG 64            // NUM_GRAPHS (fixed by the problem)
#define NMAX 2048        // max nodes per graph (mean 1563)
#define SEGCAP 4096      // max valid edges per graph (mean ~780)
#define SUBN 16          // sub-buckets per graph (atomic de-contention)
#define SUBCAP 256       // SEGCAP / SUBN; expected fill ~49

typedef _Float16 f16x8 __attribute__((ext_vector_type(8)));
typedef float f32x4 __attribute__((ext_vector_type(4)));

__device__ __forceinline__ uint4 pack8(const float* f) {
    union { uint4 u; __half2 h[4]; } v;
    v.h[0] = __floats2half2_rn(f[0], f[1]);
    v.h[1] = __floats2half2_rn(f[2], f[3]);
    v.h[2] = __floats2half2_rn(f[4], f[5]);
    v.h[3] = __floats2half2_rn(f[6], f[7]);
    return v.u;
}

// ---------------------------------------------------------------------------
// K1: zero gcnt (all 64x16 sub-counters), graph bounds, encode -> M1
// ---------------------------------------------------------------------------
__global__ __launch_bounds__(BS) void encode_kernel(
        const int* __restrict__ seq,
        const float* __restrict__ xcov,
        const int* __restrict__ batch,
        const float* __restrict__ embed,   // 6x16
        const float* __restrict__ w1,      // 17x16
        const float* __restrict__ b1,      // 16
        float* __restrict__ M1,
        int* __restrict__ gcnt,            // 64*16 sub-counters
        int* __restrict__ bnd, int N) {
    __shared__ float sE[96];
    __shared__ float sW1[272];
    __shared__ float sB1[16];
    int tid = threadIdx.x;
    for (int i = tid; i < 96; i += BS) sE[i] = embed[i];
    for (int i = tid; i < 272; i += BS) sW1[i] = w1[i];
    if (tid < 16) sB1[tid] = b1[tid];
    __syncthreads();

    if (blockIdx.x == 0) {
        for (int i = tid; i < NG * 16; i += BS) gcnt[i] = 0;
    }

    int n = blockIdx.x * BS + tid;
    if (n >= N) return;

    int b = batch[n];
    if (n == 0) {
        for (int g = 0; g <= b; g++) bnd[g] = 0;
    } else {
        int pb = batch[n - 1];
        for (int g = pb + 1; g <= b; g++) bnd[g] = n;
    }
    if (n == N - 1) {
        for (int g = b + 1; g <= NG; g++) bnd[g] = N;
    }

    const int4* t4 = (const int4*)(seq + (size_t)n * 64);
    int c1 = 0, c2 = 0, c3 = 0, c4 = 0, c5 = 0;
#pragma unroll
    for (int i = 0; i < 16; i++) {
        int4 v = t4[i];
        c1 += (v.x == 1) + (v.y == 1) + (v.z == 1) + (v.w == 1);
        c2 += (v.x == 2) + (v.y == 2) + (v.z == 2) + (v.w == 2);
        c3 += (v.x == 3) + (v.y == 3) + (v.z == 3) + (v.w == 3);
        c4 += (v.x == 4) + (v.y == 4) + (v.z == 4) + (v.w == 4);
        c5 += (v.x == 5) + (v.y == 5) + (v.z == 5) + (v.w == 5);
    }
    float f1 = (float)c1, f2 = (float)c2, f3 = (float)c3, f4 = (float)c4, f5 = (float)c5;
    float tot = f1 + f2 + f3 + f4 + f5;
    float inv = 1.0f / fmaxf(tot, 1.0f);
    float h[16];
#pragma unroll
    for (int j = 0; j < 16; j++)
        h[j] = (f1 * sE[16 + j] + f2 * sE[32 + j] + f3 * sE[48 + j] +
                f4 * sE[64 + j] + f5 * sE[80 + j]) * inv;
    float xc = xcov[n];
    float o[16];
#pragma unroll
    for (int j = 0; j < 16; j++) o[j] = sB1[j] + xc * sW1[256 + j];
#pragma unroll
    for (int k = 0; k < 16; k++) {
        float hk = h[k];
#pragma unroll
        for (int j = 0; j < 16; j++) o[j] += hk * sW1[k * 16 + j];
    }
    float4* mr = (float4*)(M1 + (size_t)n * 16);
    mr[0] = make_float4(o[0], o[1], o[2], o[3]);
    mr[1] = make_float4(o[4], o[5], o[6], o[7]);
    mr[2] = make_float4(o[8], o[9], o[10], o[11]);
    mr[3] = make_float4(o[12], o[13], o[14], o[15]);
}

// ---------------------------------------------------------------------------
// K2: prep — validity via LDS bound search, bucket valid edges per graph.
// ---------------------------------------------------------------------------
__device__ __forceinline__ int find_graph(const int* bnd, int s) {
    int g = 0;
#pragma unroll
    for (int step = 32; step; step >>= 1) {
        int c = g + step;
        if (c <= NG - 1 && bnd[c] <= s) g = c;
    }
    return g;
}

__global__ __launch_bounds__(BS) void prep_kernel(
        const int* __restrict__ ei,
        const int* __restrict__ bndg,
        int2* __restrict__ glist,
        int* __restrict__ gcnt, int E) {
    __shared__ int sBnd[NG + 1];
    int tid = threadIdx.x;
    if (tid <= NG) sBnd[tid] = bndg[tid];
    __syncthreads();

    int sub = blockIdx.x & (SUBN - 1);
    int idx = (blockIdx.x * BS + tid) * 4;
    if (idx + 3 < E) {
        int4 s4 = *(const int4*)(ei + idx);
        int4 d4 = *(const int4*)(ei + E + idx);
#pragma unroll
        for (int j = 0; j < 4; j++) {
            int s = (&s4.x)[j], d = (&d4.x)[j];
            int g = find_graph(sBnd, s);
            if (d >= sBnd[g] && d < sBnd[g + 1]) {
                int pos = atomicAdd(&gcnt[g * 16 + sub], 1);
                if (pos < SUBCAP)
                    glist[(size_t)g * SEGCAP + sub * SUBCAP + pos] = make_int2(s, d);
            }
        }
    } else {
        for (int j = 0; j < 4; j++) {
            int e = idx + j;
            if (e < E) {
                int s = ei[e], d = ei[E + e];
                int g = find_graph(sBnd, s);
                if (d >= sBnd[g] && d < sBnd[g + 1]) {
                    int pos = atomicAdd(&gcnt[g * 16 + sub], 1);
                    if (pos < SUBCAP)
                        glist[(size_t)g * SEGCAP + sub * SUBCAP + pos] = make_int2(s, d);
                }
            }
        }
    }
}

// ---------------------------------------------------------------------------
// K3a: one block per graph. Counting-sort CSR into GLOBAL arrays.
// ---------------------------------------------------------------------------
__global__ __launch_bounds__(BS3) void csr_kernel(
        const int2* __restrict__ glist,
        const int* __restrict__ gcnt,
        const int* __restrict__ bnd,
        int2* __restrict__ OD,
        float* __restrict__ Dinv,
        int* __restrict__ csrD) {
    __shared__ int hist[NMAX];
    __shared__ int off[NMAX + 1];
    __shared__ int cur[NMAX];
    __shared__ int wsum[4];
    __shared__ int sCnt[SUBN];

    int tid = threadIdx.x;
    int g = blockIdx.x;
    int lo = bnd[g], hi = bnd[g + 1];
    int ng = hi - lo;
    if (ng > NMAX) ng = NMAX;

    for (int i = tid; i < NMAX; i += BS3) hist[i] = 0;
    if (tid < SUBN) {
        int c = gcnt[g * 16 + tid];
        sCnt[tid] = (c > SUBCAP) ? SUBCAP : c;
    }
    __syncthreads();

    if (ng <= 0) return;

    const int2* seg = glist + (size_t)g * SEGCAP;

    for (int idx = tid; idx < SUBN * SUBCAP; idx += BS3) {
        int c = idx >> 8;
        int k = idx & (SUBCAP - 1);
        if (k < sCnt[c]) atomicAdd(&hist[seg[c * SUBCAP + k].x - lo], 1);
    }
    __syncthreads();

    int i0 = tid * 8;
    int lv[8];
    int s = 0;
#pragma unroll
    for (int k = 0; k < 8; k++) { lv[k] = hist[i0 + k]; s += lv[k]; }
    int lane = tid & 63, wv = tid >> 6;
    int x = s;
#pragma unroll
    for (int o = 1; o < 64; o <<= 1) {
        int y = __shfl_up(x, o);
        if (lane >= o) x += y;
    }
    if (lane == 63) wsum[wv] = x;
    __syncthreads();
    if (wv == 0 && lane < 4) {
        int w = wsum[lane];
#pragma unroll
        for (int o = 1; o < 4; o <<= 1) {
            int y = __shfl_up(w, o);
            if (lane >= o) w += y;
        }
        wsum[lane] = w;
    }
    __syncthreads();
    int base = (wv > 0) ? wsum[wv - 1] : 0;
    int excl = base + x - s;
    int run = excl;
#pragma unroll
    for (int k = 0; k < 8; k++) {
        off[i0 + k] = run;
        cur[i0 + k] = run;
        run += lv[k];
    }
    __syncthreads();

    int gbase = g * SEGCAP;
    for (int i = tid; i < ng; i += BS3) {
        int beg = off[i];
        int dg = ((i + 1 < NMAX) ? off[i + 1] : beg) - beg;
        OD[lo + i] = make_int2(gbase + beg, dg);
        float dgf = (float)dg + 1.0f + 1e-8f;
        Dinv[lo + i] = 1.0f / sqrtf(dgf);
    }

    for (int idx = tid; idx < SUBN * SUBCAP; idx += BS3) {
        int c = idx >> 8;
        int k = idx & (SUBCAP - 1);
        if (k < sCnt[c]) {
            int2 e = seg[c * SUBCAP + k];
            int pos = atomicAdd(&cur[e.x - lo], 1);
            csrD[gbase + pos] = e.y;
        }
    }
}

// ---------------------------------------------------------------------------
// K3b: GCN layer 1, node-parallel. M2 <- (relu(dinv*(agg + dinv*M1))) @ w2 + b2
// ---------------------------------------------------------------------------
__global__ __launch_bounds__(BS) void layer1_kernel(
        const int2* __restrict__ OD,
        const float* __restrict__ Dinv,
        const int* __restrict__ csrD,
        const float* __restrict__ M1,
        float* __restrict__ M2,
        const float* __restrict__ w2,      // 16x16
        const float* __restrict__ b2,      // 16
        int N) {
    __shared__ float sW2[256];
    __shared__ float sB2[16];
    int tid = threadIdx.x;
    for (int i = tid; i < 256; i += BS) sW2[i] = w2[i];
    if (tid < 16) sB2[tid] = b2[tid];
    __syncthreads();

    int n = blockIdx.x * BS + tid;
    if (n >= N) return;

    int2 od = OD[n];
    float di = Dinv[n];
    float acc[16];
#pragma unroll
    for (int j = 0; j < 16; j++) acc[j] = 0.f;
    int end = od.x + od.y;
    for (int e = od.x; e < end; e++) {
        int d = csrD[e];
        float dd = Dinv[d];
        const float4* m4 = (const float4*)(M1 + (size_t)d * 16);
        float4 a = m4[0], b = m4[1], c = m4[2], q = m4[3];
        acc[0] += dd * a.x; acc[1] += dd * a.y; acc[2] += dd * a.z; acc[3] += dd * a.w;
        acc[4] += dd * b.x; acc[5] += dd * b.y; acc[6] += dd * b.z; acc[7] += dd * b.w;
        acc[8] += dd * c.x; acc[9] += dd * c.y; acc[10] += dd * c.z; acc[11] += dd * c.w;
        acc[12] += dd * q.x; acc[13] += dd * q.y; acc[14] += dd * q.z; acc[15] += dd * q.w;
    }
    const float4* mr = (const float4*)(M1 + (size_t)n * 16);
    float4 m0 = mr[0], m1 = mr[1], m2 = mr[2], m3 = mr[3];
    float m[16] = {m0.x,m0.y,m0.z,m0.w, m1.x,m1.y,m1.z,m1.w,
                   m2.x,m2.y,m2.z,m2.w, m3.x,m3.y,m3.z,m3.w};
    float h[16];
#pragma unroll
    for (int j = 0; j < 16; j++) h[j] = fmaxf(di * (acc[j] + di * m[j]), 0.0f);
    float o[16];
#pragma unroll
    for (int j = 0; j < 16; j++) o[j] = sB2[j];
#pragma unroll
    for (int k = 0; k < 16; k++) {
        float hk = h[k];
#pragma unroll
        for (int j = 0; j < 16; j++) o[j] += hk * sW2[k * 16 + j];
    }
    float4* wr = (float4*)(M2 + (size_t)n * 16);
    wr[0] = make_float4(o[0], o[1], o[2], o[3]);
    wr[1] = make_float4(o[4], o[5], o[6], o[7]);
    wr[2] = make_float4(o[8], o[9], o[10], o[11]);
    wr[3] = make_float4(o[12], o[13], o[14], o[15]);
}

// ---------------------------------------------------------------------------
// K3c: GCN layer 2, node-parallel. H2 -> Hf (16 x f16 = 32 B/node).
// ---------------------------------------------------------------------------
__global__ __launch_bounds__(BS) void layer2_kernel(
        const int2* __restrict__ OD,
        const float* __restrict__ Dinv,
        const int* __restrict__ csrD,
        const float* __restrict__ M2,
        char* __restrict__ Hf,             // N x 32 B f16 rows
        int N) {
    int tid = threadIdx.x;
    int n = blockIdx.x * BS + tid;
    if (n >= N) return;

    int2 od = OD[n];
    float di = Dinv[n];
    float acc[16];
#pragma unroll
    for (int j = 0; j < 16; j++) acc[j] = 0.f;
    int end = od.x + od.y;
    for (int e = od.x; e < end; e++) {
        int d = csrD[e];
        float dd = Dinv[d];
        const float4* m4 = (const float4*)(M2 + (size_t)d * 16);
        float4 a = m4[0], b = m4[1], c = m4[2], q = m4[3];
        acc[0] += dd * a.x; acc[1] += dd * a.y; acc[2] += dd * a.z; acc[3] += dd * a.w;
        acc[4] += dd * b.x; acc[5] += dd * b.y; acc[6] += dd * b.z; acc[7] += dd * b.w;
        acc[8] += dd * c.x; acc[9] += dd * c.y; acc[10] += dd * c.z; acc[11] += dd * c.w;
        acc[12] += dd * q.x; acc[13] += dd * q.y; acc[14] += dd * q.z; acc[15] += dd * q.w;
    }
    const float4* mr = (const float4*)(M2 + (size_t)n * 16);
    float4 m0 = mr[0], m1 = mr[1], m2 = mr[2], m3 = mr[3];
    float m[16] = {m0.x,m0.y,m0.z,m0.w, m1.x,m1.y,m1.z,m1.w,
                   m2.x,m2.y,m2.z,m2.w, m3.x,m3.y,m3.z,m3.w};
    float h[16];
#pragma unroll
    for (int j = 0; j < 16; j++) h[j] = fmaxf(di * (acc[j] + di * m[j]), 0.0f);
    uint4* pr = (uint4*)(Hf + (size_t)n * 32);
    pr[0] = pack8(h); pr[1] = pack8(h + 8);
}

// ---------------------------------------------------------------------------
// K4: edge MLP via MFMA, epilogue folded into the C-operand.
//   u[j] = be1[j] + sum_i a_i*we1[32+i][j]  (per edge, staged in LDS, 2-way)
//   acc  = [hs|hd] @ we1[0:32]  + u        (single mfma per 16 edges)
//   logit= be2 + sum_j relu(acc[.,j])*we2[j]  (shfl_xor reduce over j)
// No C round-trip through LDS; 8-way-conflicted readback removed.
// ---------------------------------------------------------------------------
__global__ __launch_bounds__(BS) void edge_mlp_kernel(
        const int* __restrict__ ei,
        const char* __restrict__ Hf,       // N x 32 B f16 h-rows
        const float* __restrict__ eattr,   // E x 5 f32
        const float* __restrict__ we1,     // 37x16 f32
        const float* __restrict__ be1,     // 16
        const float* __restrict__ we2,     // 16
        const float* __restrict__ be2,     // 1
        float* __restrict__ out, int E) {
    __shared__ __align__(16) char sA[4 * 5120];      // per-wave A: 64 rows x 80B (32 f16 used)
    __shared__ float sU[4 * 64 * 18];                // per-wave U: 64 rows x 18 f32 (16 used)
    __shared__ float sCw[80];   // we1 rows 32..36
    __shared__ float sBw[16];
    __shared__ float sVw[16];
    __shared__ float sb2v;
    int tid = threadIdx.x;
    int w = tid >> 6, lane = tid & 63;
    if (tid < 80) sCw[tid] = we1[512 + tid];
    if (tid < 16) { sBw[tid] = be1[tid]; sVw[tid] = we2[tid]; }
    if (tid == 0) sb2v = be2[0];

    int e0 = blockIdx.x * BS;
    int e = e0 + tid;
    int ec = e < E ? e : (E - 1);
    int s = __builtin_nontemporal_load(ei + ec);
    int d = __builtin_nontemporal_load(ei + E + ec);
    const float* ea = eattr + (size_t)ec * 5;
    float a0 = __builtin_nontemporal_load(ea + 0);
    float a1 = __builtin_nontemporal_load(ea + 1);
    float a2 = __builtin_nontemporal_load(ea + 2);
    float a3 = __builtin_nontemporal_load(ea + 3);
    float a4 = __builtin_nontemporal_load(ea + 4);

    // h gathers (3.2 MB table, L2-resident): plain loads
    const uint4* hsp = (const uint4*)(Hf + (size_t)s * 32);
    uint4 hs0 = hsp[0], hs1 = hsp[1];
    const uint4* hdp = (const uint4*)(Hf + (size_t)d * 32);
    uint4 hd0 = hdp[0], hd1 = hdp[1];

    // B fragment: Wcat[k][j] = we1[k*16+j]; lane holds col (lane&15), k-slice (lane>>4)*8
    f16x8 bf;
    {
        const float* wr = we1 + ((lane >> 4) * 8) * 16 + (lane & 15);
#pragma unroll
        for (int i = 0; i < 8; i++) bf[i] = (_Float16)wr[i * 16];
    }

    // A-tile: row = in-tile edge = lane; 32 f16 = [hs|hd]; 80-B rows (2-way banks)
    char* A = sA + w * 5120;
    {
        uint4* trow = (uint4*)(A + lane * 80);
        trow[0] = hs0; trow[1] = hs1; trow[2] = hd0; trow[3] = hd1;
    }
    __syncthreads();   // consts + A visible

    // u for own edge -> U tile (stride 18 f32: writes/reads both ~2-way = free)
    float* U = sU + w * 64 * 18;
#pragma unroll
    for (int j = 0; j < 16; j++) {
        float u = sBw[j] + a0 * sCw[j] + a1 * sCw[16 + j] + a2 * sCw[32 + j] +
                  a3 * sCw[48 + j] + a4 * sCw[64 + j];
        U[lane * 18 + j] = u;
    }
    __syncthreads();   // U visible

    float sv = sVw[lane & 15];
#pragma unroll
    for (int q = 0; q < 4; q++) {
        // A-frag: row (q*16 + lane&15), k-chunk (lane>>4)*8
        f16x8 af = *(const f16x8*)(A + (q * 16 + (lane & 15)) * 80 + (lane >> 4) * 16);
        int rbase = q * 16 + (lane >> 4) * 4;
        // C-frag = u rows rbase..rbase+3, col lane&15
        f32x4 cin;
#pragma unroll
        for (int r = 0; r < 4; r++) cin[r] = U[(rbase + r) * 18 + (lane & 15)];
        f32x4 acc = __builtin_amdgcn_mfma_f32_16x16x32_f16(af, bf, cin, 0, 0, 0);
        // relu * V[j], reduce over j (16-lane group), store by j==0 lanes
        float pl[4];
#pragma unroll
        for (int r = 0; r < 4; r++) pl[r] = fmaxf(acc[r], 0.0f) * sv;
#pragma unroll
        for (int m = 1; m < 16; m <<= 1) {
#pragma unroll
            for (int r = 0; r < 4; r++) pl[r] += __shfl_xor(pl[r], m);
        }
        if ((lane & 15) == 0) {
#pragma unroll
            for (int r = 0; r < 4; r++) {
                int ee = e0 + w * 64 + rbase + r;
                if (ee < E) __builtin_nontemporal_store(pl[r] + sb2v, out + ee);
            }
        }
    }
}

// ---------------------------------------------------------------------------
extern "C" void kernel_launch(void* const* d_in, const int* in_sizes, int n_in,
                              void* d_out, int out_size, void* d_ws, size_t ws_size,
                              hipStream_t stream) {
    const int* seq     = (const int*)d_in[0];
    const float* xcov  = (const float*)d_in[1];
    const int* ei      = (const int*)d_in[2];
    const float* eattr = (const float*)d_in[3];
    const int* batch   = (const int*)d_in[4];
    const float* embed = (const float*)d_in[5];
    const float* w1    = (const float*)d_in[6];
    const float* b1    = (const float*)d_in[7];
    const float* w2    = (const float*)d_in[8];
    const float* b2    = (const float*)d_in[9];
    const float* we1   = (const float*)d_in[10];
    const float* be1   = (const float*)d_in[11];
    const float* we2   = (const float*)d_in[12];
    const float* be2   = (const float*)d_in[13];
    float* out         = (float*)d_out;   // fp32 output

    int N = in_sizes[1];
    int E = in_sizes[2] / 2;

    char* ws = (char*)d_ws;
    size_t off_b = 0;
    auto alloc = [&](size_t bytes) -> void* {
        void* p = ws + off_b;
        off_b += (bytes + 255) & ~(size_t)255;
        return p;
    };
    float* M1    = (float*)alloc((size_t)N * 16 * sizeof(float));
    float* M2    = (float*)alloc((size_t)N * 16 * sizeof(float));
    char* Hf     = (char*)alloc((size_t)N * 32);
    int* bndg    = (int*)alloc((NG + 1) * sizeof(int));
    int* gcnt    = (int*)alloc(NG * 16 * sizeof(int));
    int2* glist  = (int2*)alloc((size_t)NG * SEGCAP * sizeof(int2));
    int2* OD     = (int2*)alloc((size_t)N * sizeof(int2));
    float* Dinv  = (float*)alloc((size_t)N * sizeof(float));
    int* csrD    = (int*)alloc((size_t)NG * SEGCAP * sizeof(int));

    int gn = (N + BS - 1) / BS;
    int gp = (E + BS * 4 - 1) / (BS * 4);
    int ge = (E + BS - 1) / BS;

    encode_kernel<<<gn, BS, 0, stream>>>(seq, xcov, batch, embed, w1, b1,
                                         M1, gcnt, bndg, N);
    prep_kernel<<<gp, BS, 0, stream>>>(ei, bndg, glist, gcnt, E);
    csr_kernel<<<NG, BS3, 0, stream>>>(glist, gcnt, bndg, OD, Dinv, csrD);
    layer1_kernel<<<gn, BS, 0, stream>>>(OD, Dinv, csrD, M1, M2, w2, b2, N);
    layer2_kernel<<<gn, BS, 0, stream>>>(OD, Dinv, csrD, M2, Hf, N);
    edge_mlp_kernel<<<ge, BS, 0, stream>>>(ei, Hf, eattr, we1, be1, we2, be2, out, E);
}

// Round 9
// 254.577 us; speedup vs baseline: 1.0624x; 1.0624x over previous
//
#include <hip/hip_runtime.h>
#include <hip/hip_bf16.h>
#include <hip/hip_fp16.h>

#define BS 256
#define BS3 256          // csr kernel block size
#define NG 64            // NUM_GRAPHS (fixed by the problem)
#define NMAX 2048        // max nodes per graph (mean 1563)
#define SEGCAP 4096      // max valid edges per graph (mean ~780)
#define SUBN 16          // sub-buckets per graph (atomic de-contention)
#define SUBCAP 256       // SEGCAP / SUBN; expected fill ~49

typedef _Float16 f16x8 __attribute__((ext_vector_type(8)));
typedef float f32x4 __attribute__((ext_vector_type(4)));

__device__ __forceinline__ uint4 pack8(const float* f) {
    union { uint4 u; __half2 h[4]; } v;
    v.h[0] = __floats2half2_rn(f[0], f[1]);
    v.h[1] = __floats2half2_rn(f[2], f[3]);
    v.h[2] = __floats2half2_rn(f[4], f[5]);
    v.h[3] = __floats2half2_rn(f[6], f[7]);
    return v.u;
}

// ---------------------------------------------------------------------------
// K1: zero gcnt (all 64x16 sub-counters), graph bounds, encode -> M1
// ---------------------------------------------------------------------------
__global__ __launch_bounds__(BS) void encode_kernel(
        const int* __restrict__ seq,
        const float* __restrict__ xcov,
        const int* __restrict__ batch,
        const float* __restrict__ embed,   // 6x16
        const float* __restrict__ w1,      // 17x16
        const float* __restrict__ b1,      // 16
        float* __restrict__ M1,
        int* __restrict__ gcnt,            // 64*16 sub-counters
        int* __restrict__ bnd, int N) {
    __shared__ float sE[96];
    __shared__ float sW1[272];
    __shared__ float sB1[16];
    int tid = threadIdx.x;
    for (int i = tid; i < 96; i += BS) sE[i] = embed[i];
    for (int i = tid; i < 272; i += BS) sW1[i] = w1[i];
    if (tid < 16) sB1[tid] = b1[tid];
    __syncthreads();

    if (blockIdx.x == 0) {
        for (int i = tid; i < NG * 16; i += BS) gcnt[i] = 0;
    }

    int n = blockIdx.x * BS + tid;
    if (n >= N) return;

    int b = batch[n];
    if (n == 0) {
        for (int g = 0; g <= b; g++) bnd[g] = 0;
    } else {
        int pb = batch[n - 1];
        for (int g = pb + 1; g <= b; g++) bnd[g] = n;
    }
    if (n == N - 1) {
        for (int g = b + 1; g <= NG; g++) bnd[g] = N;
    }

    const int4* t4 = (const int4*)(seq + (size_t)n * 64);
    int c1 = 0, c2 = 0, c3 = 0, c4 = 0, c5 = 0;
#pragma unroll
    for (int i = 0; i < 16; i++) {
        int4 v = t4[i];
        c1 += (v.x == 1) + (v.y == 1) + (v.z == 1) + (v.w == 1);
        c2 += (v.x == 2) + (v.y == 2) + (v.z == 2) + (v.w == 2);
        c3 += (v.x == 3) + (v.y == 3) + (v.z == 3) + (v.w == 3);
        c4 += (v.x == 4) + (v.y == 4) + (v.z == 4) + (v.w == 4);
        c5 += (v.x == 5) + (v.y == 5) + (v.z == 5) + (v.w == 5);
    }
    float f1 = (float)c1, f2 = (float)c2, f3 = (float)c3, f4 = (float)c4, f5 = (float)c5;
    float tot = f1 + f2 + f3 + f4 + f5;
    float inv = 1.0f / fmaxf(tot, 1.0f);
    float h[16];
#pragma unroll
    for (int j = 0; j < 16; j++)
        h[j] = (f1 * sE[16 + j] + f2 * sE[32 + j] + f3 * sE[48 + j] +
                f4 * sE[64 + j] + f5 * sE[80 + j]) * inv;
    float xc = xcov[n];
    float o[16];
#pragma unroll
    for (int j = 0; j < 16; j++) o[j] = sB1[j] + xc * sW1[256 + j];
#pragma unroll
    for (int k = 0; k < 16; k++) {
        float hk = h[k];
#pragma unroll
        for (int j = 0; j < 16; j++) o[j] += hk * sW1[k * 16 + j];
    }
    float4* mr = (float4*)(M1 + (size_t)n * 16);
    mr[0] = make_float4(o[0], o[1], o[2], o[3]);
    mr[1] = make_float4(o[4], o[5], o[6], o[7]);
    mr[2] = make_float4(o[8], o[9], o[10], o[11]);
    mr[3] = make_float4(o[12], o[13], o[14], o[15]);
}

// ---------------------------------------------------------------------------
// K2: prep — validity via LDS bound search, bucket valid edges per graph.
// ---------------------------------------------------------------------------
__device__ __forceinline__ int find_graph(const int* bnd, int s) {
    int g = 0;
#pragma unroll
    for (int step = 32; step; step >>= 1) {
        int c = g + step;
        if (c <= NG - 1 && bnd[c] <= s) g = c;
    }
    return g;
}

__global__ __launch_bounds__(BS) void prep_kernel(
        const int* __restrict__ ei,
        const int* __restrict__ bndg,
        int2* __restrict__ glist,
        int* __restrict__ gcnt, int E) {
    __shared__ int sBnd[NG + 1];
    int tid = threadIdx.x;
    if (tid <= NG) sBnd[tid] = bndg[tid];
    __syncthreads();

    int sub = blockIdx.x & (SUBN - 1);
    int idx = (blockIdx.x * BS + tid) * 4;
    if (idx + 3 < E) {
        int4 s4 = *(const int4*)(ei + idx);
        int4 d4 = *(const int4*)(ei + E + idx);
#pragma unroll
        for (int j = 0; j < 4; j++) {
            int s = (&s4.x)[j], d = (&d4.x)[j];
            int g = find_graph(sBnd, s);
            if (d >= sBnd[g] && d < sBnd[g + 1]) {
                int pos = atomicAdd(&gcnt[g * 16 + sub], 1);
                if (pos < SUBCAP)
                    glist[(size_t)g * SEGCAP + sub * SUBCAP + pos] = make_int2(s, d);
            }
        }
    } else {
        for (int j = 0; j < 4; j++) {
            int e = idx + j;
            if (e < E) {
                int s = ei[e], d = ei[E + e];
                int g = find_graph(sBnd, s);
                if (d >= sBnd[g] && d < sBnd[g + 1]) {
                    int pos = atomicAdd(&gcnt[g * 16 + sub], 1);
                    if (pos < SUBCAP)
                        glist[(size_t)g * SEGCAP + sub * SUBCAP + pos] = make_int2(s, d);
                }
            }
        }
    }
}

// ---------------------------------------------------------------------------
// K3a: one block per graph. Counting-sort CSR into GLOBAL arrays.
// ---------------------------------------------------------------------------
__global__ __launch_bounds__(BS3) void csr_kernel(
        const int2* __restrict__ glist,
        const int* __restrict__ gcnt,
        const int* __restrict__ bnd,
        int2* __restrict__ OD,
        float* __restrict__ Dinv,
        int* __restrict__ csrD) {
    __shared__ int hist[NMAX];
    __shared__ int off[NMAX + 1];
    __shared__ int cur[NMAX];
    __shared__ int wsum[4];
    __shared__ int sCnt[SUBN];

    int tid = threadIdx.x;
    int g = blockIdx.x;
    int lo = bnd[g], hi = bnd[g + 1];
    int ng = hi - lo;
    if (ng > NMAX) ng = NMAX;

    for (int i = tid; i < NMAX; i += BS3) hist[i] = 0;
    if (tid < SUBN) {
        int c = gcnt[g * 16 + tid];
        sCnt[tid] = (c > SUBCAP) ? SUBCAP : c;
    }
    __syncthreads();

    if (ng <= 0) return;

    const int2* seg = glist + (size_t)g * SEGCAP;

    for (int idx = tid; idx < SUBN * SUBCAP; idx += BS3) {
        int c = idx >> 8;
        int k = idx & (SUBCAP - 1);
        if (k < sCnt[c]) atomicAdd(&hist[seg[c * SUBCAP + k].x - lo], 1);
    }
    __syncthreads();

    int i0 = tid * 8;
    int lv[8];
    int s = 0;
#pragma unroll
    for (int k = 0; k < 8; k++) { lv[k] = hist[i0 + k]; s += lv[k]; }
    int lane = tid & 63, wv = tid >> 6;
    int x = s;
#pragma unroll
    for (int o = 1; o < 64; o <<= 1) {
        int y = __shfl_up(x, o);
        if (lane >= o) x += y;
    }
    if (lane == 63) wsum[wv] = x;
    __syncthreads();
    if (wv == 0 && lane < 4) {
        int w = wsum[lane];
#pragma unroll
        for (int o = 1; o < 4; o <<= 1) {
            int y = __shfl_up(w, o);
            if (lane >= o) w += y;
        }
        wsum[lane] = w;
    }
    __syncthreads();
    int base = (wv > 0) ? wsum[wv - 1] : 0;
    int excl = base + x - s;
    int run = excl;
#pragma unroll
    for (int k = 0; k < 8; k++) {
        off[i0 + k] = run;
        cur[i0 + k] = run;
        run += lv[k];
    }
    __syncthreads();

    int gbase = g * SEGCAP;
    for (int i = tid; i < ng; i += BS3) {
        int beg = off[i];
        int dg = ((i + 1 < NMAX) ? off[i + 1] : beg) - beg;
        OD[lo + i] = make_int2(gbase + beg, dg);
        float dgf = (float)dg + 1.0f + 1e-8f;
        Dinv[lo + i] = 1.0f / sqrtf(dgf);
    }

    for (int idx = tid; idx < SUBN * SUBCAP; idx += BS3) {
        int c = idx >> 8;
        int k = idx & (SUBCAP - 1);
        if (k < sCnt[c]) {
            int2 e = seg[c * SUBCAP + k];
            int pos = atomicAdd(&cur[e.x - lo], 1);
            csrD[gbase + pos] = e.y;
        }
    }
}

// ---------------------------------------------------------------------------
// K3b: GCN layer 1, node-parallel. M2 <- (relu(dinv*(agg + dinv*M1))) @ w2 + b2
// ---------------------------------------------------------------------------
__global__ __launch_bounds__(BS) void layer1_kernel(
        const int2* __restrict__ OD,
        const float* __restrict__ Dinv,
        const int* __restrict__ csrD,
        const float* __restrict__ M1,
        float* __restrict__ M2,
        const float* __restrict__ w2,      // 16x16
        const float* __restrict__ b2,      // 16
        int N) {
    __shared__ float sW2[256];
    __shared__ float sB2[16];
    int tid = threadIdx.x;
    for (int i = tid; i < 256; i += BS) sW2[i] = w2[i];
    if (tid < 16) sB2[tid] = b2[tid];
    __syncthreads();

    int n = blockIdx.x * BS + tid;
    if (n >= N) return;

    int2 od = OD[n];
    float di = Dinv[n];
    float acc[16];
#pragma unroll
    for (int j = 0; j < 16; j++) acc[j] = 0.f;
    int end = od.x + od.y;
    for (int e = od.x; e < end; e++) {
        int d = csrD[e];
        float dd = Dinv[d];
        const float4* m4 = (const float4*)(M1 + (size_t)d * 16);
        float4 a = m4[0], b = m4[1], c = m4[2], q = m4[3];
        acc[0] += dd * a.x; acc[1] += dd * a.y; acc[2] += dd * a.z; acc[3] += dd * a.w;
        acc[4] += dd * b.x; acc[5] += dd * b.y; acc[6] += dd * b.z; acc[7] += dd * b.w;
        acc[8] += dd * c.x; acc[9] += dd * c.y; acc[10] += dd * c.z; acc[11] += dd * c.w;
        acc[12] += dd * q.x; acc[13] += dd * q.y; acc[14] += dd * q.z; acc[15] += dd * q.w;
    }
    const float4* mr = (const float4*)(M1 + (size_t)n * 16);
    float4 m0 = mr[0], m1 = mr[1], m2 = mr[2], m3 = mr[3];
    float m[16] = {m0.x,m0.y,m0.z,m0.w, m1.x,m1.y,m1.z,m1.w,
                   m2.x,m2.y,m2.z,m2.w, m3.x,m3.y,m3.z,m3.w};
    float h[16];
#pragma unroll
    for (int j = 0; j < 16; j++) h[j] = fmaxf(di * (acc[j] + di * m[j]), 0.0f);
    float o[16];
#pragma unroll
    for (int j = 0; j < 16; j++) o[j] = sB2[j];
#pragma unroll
    for (int k = 0; k < 16; k++) {
        float hk = h[k];
#pragma unroll
        for (int j = 0; j < 16; j++) o[j] += hk * sW2[k * 16 + j];
    }
    float4* wr = (float4*)(M2 + (size_t)n * 16);
    wr[0] = make_float4(o[0], o[1], o[2], o[3]);
    wr[1] = make_float4(o[4], o[5], o[6], o[7]);
    wr[2] = make_float4(o[8], o[9], o[10], o[11]);
    wr[3] = make_float4(o[12], o[13], o[14], o[15]);
}

// ---------------------------------------------------------------------------
// K3c: GCN layer 2, node-parallel. H2 -> Hf (16 x f16 = 32 B/node).
// ---------------------------------------------------------------------------
__global__ __launch_bounds__(BS) void layer2_kernel(
        const int2* __restrict__ OD,
        const float* __restrict__ Dinv,
        const int* __restrict__ csrD,
        const float* __restrict__ M2,
        char* __restrict__ Hf,             // N x 32 B f16 rows
        int N) {
    int tid = threadIdx.x;
    int n = blockIdx.x * BS + tid;
    if (n >= N) return;

    int2 od = OD[n];
    float di = Dinv[n];
    float acc[16];
#pragma unroll
    for (int j = 0; j < 16; j++) acc[j] = 0.f;
    int end = od.x + od.y;
    for (int e = od.x; e < end; e++) {
        int d = csrD[e];
        float dd = Dinv[d];
        const float4* m4 = (const float4*)(M2 + (size_t)d * 16);
        float4 a = m4[0], b = m4[1], c = m4[2], q = m4[3];
        acc[0] += dd * a.x; acc[1] += dd * a.y; acc[2] += dd * a.z; acc[3] += dd * a.w;
        acc[4] += dd * b.x; acc[5] += dd * b.y; acc[6] += dd * b.z; acc[7] += dd * b.w;
        acc[8] += dd * c.x; acc[9] += dd * c.y; acc[10] += dd * c.z; acc[11] += dd * c.w;
        acc[12] += dd * q.x; acc[13] += dd * q.y; acc[14] += dd * q.z; acc[15] += dd * q.w;
    }
    const float4* mr = (const float4*)(M2 + (size_t)n * 16);
    float4 m0 = mr[0], m1 = mr[1], m2 = mr[2], m3 = mr[3];
    float m[16] = {m0.x,m0.y,m0.z,m0.w, m1.x,m1.y,m1.z,m1.w,
                   m2.x,m2.y,m2.z,m2.w, m3.x,m3.y,m3.z,m3.w};
    float h[16];
#pragma unroll
    for (int j = 0; j < 16; j++) h[j] = fmaxf(di * (acc[j] + di * m[j]), 0.0f);
    uint4* pr = (uint4*)(Hf + (size_t)n * 32);
    pr[0] = pack8(h); pr[1] = pack8(h + 8);
}

// ---------------------------------------------------------------------------
// K4: edge MLP via MFMA with SWAPPED operands (C^T fragment layout).
//   acc^T = Wcat^T @ [hs|hd]^T + u^T   via  mfma(bf, af, cin)
//   -> lane holds edge = lane&15 (of 16-edge group q), j = (lane>>4)*4 + r.
//   Epilogue fully in-register: relu*V, sum over own 4 j's, 2x shfl_xor to
//   sum the 4 j-groups, 16 consecutive lanes store 16 consecutive floats
//   (full 64B line => no NT write amplification). Per-lane we1/be1/we2
//   constants hoisted to registers; only A-tile + 5 attr floats in LDS.
// ---------------------------------------------------------------------------
__global__ __launch_bounds__(BS) void edge_mlp_kernel(
        const int* __restrict__ ei,
        const char* __restrict__ Hf,       // N x 32 B f16 h-rows
        const float* __restrict__ eattr,   // E x 5 f32
        const float* __restrict__ we1,     // 37x16 f32
        const float* __restrict__ be1,     // 16
        const float* __restrict__ we2,     // 16
        const float* __restrict__ be2,     // 1
        float* __restrict__ out, int E) {
    __shared__ __align__(16) char sA[4 * 5120];   // per-wave A: 64 rows x 80B
    __shared__ float sAt[4 * 64 * 6];             // per-wave attr, stride 6 f32
    int tid = threadIdx.x;
    int w = tid >> 6, lane = tid & 63;

    int e0 = blockIdx.x * BS;
    int e = e0 + tid;
    int ec = e < E ? e : (E - 1);
    int s = __builtin_nontemporal_load(ei + ec);
    int d = __builtin_nontemporal_load(ei + E + ec);
    const float* ea = eattr + (size_t)ec * 5;
    float a0 = __builtin_nontemporal_load(ea + 0);
    float a1 = __builtin_nontemporal_load(ea + 1);
    float a2 = __builtin_nontemporal_load(ea + 2);
    float a3 = __builtin_nontemporal_load(ea + 3);
    float a4 = __builtin_nontemporal_load(ea + 4);

    // h gathers (3.2 MB table, L2-resident)
    const uint4* hsp = (const uint4*)(Hf + (size_t)s * 32);
    uint4 hs0 = hsp[0], hs1 = hsp[1];
    const uint4* hdp = (const uint4*)(Hf + (size_t)d * 32);
    uint4 hd0 = hdp[0], hd1 = hdp[1];

    // Wcat^T fragment (first MFMA operand): lane -> col j=lane&15, k-octet lane>>4
    f16x8 bf;
    {
        const float* wr = we1 + ((lane >> 4) * 8) * 16 + (lane & 15);
#pragma unroll
        for (int i = 0; i < 8; i++) bf[i] = (_Float16)wr[i * 16];
    }

    // per-lane epilogue constants in registers (j0..j0+3 fixed per lane)
    int j0 = (lane >> 4) * 4;
    float cw0[4], cw1[4], cw2[4], cw3[4], cw4[4], ub[4], vb[4];
#pragma unroll
    for (int r = 0; r < 4; r++) {
        ub[r] = be1[j0 + r];
        vb[r] = we2[j0 + r];
        cw0[r] = we1[32 * 16 + j0 + r];
        cw1[r] = we1[33 * 16 + j0 + r];
        cw2[r] = we1[34 * 16 + j0 + r];
        cw3[r] = we1[35 * 16 + j0 + r];
        cw4[r] = we1[36 * 16 + j0 + r];
    }
    float b2v = be2[0];

    // stage A row (edge = lane) + attr
    char* A = sA + w * 5120;
    {
        uint4* trow = (uint4*)(A + lane * 80);
        trow[0] = hs0; trow[1] = hs1; trow[2] = hd0; trow[3] = hd1;
    }
    float* At = sAt + w * 64 * 6;
    At[lane * 6 + 0] = a0; At[lane * 6 + 1] = a1; At[lane * 6 + 2] = a2;
    At[lane * 6 + 3] = a3; At[lane * 6 + 4] = a4;
    __syncthreads();

#pragma unroll
    for (int q = 0; q < 4; q++) {
        // second operand: edge tile rows q*16+(lane&15), k-octet lane>>4
        f16x8 af = *(const f16x8*)(A + (q * 16 + (lane & 15)) * 80 + (lane >> 4) * 16);
        int eIn = q * 16 + (lane & 15);
        float t0 = At[eIn * 6 + 0], t1 = At[eIn * 6 + 1], t2 = At[eIn * 6 + 2];
        float t3 = At[eIn * 6 + 3], t4 = At[eIn * 6 + 4];
        f32x4 cin;
#pragma unroll
        for (int r = 0; r < 4; r++)
            cin[r] = ub[r] + t0 * cw0[r] + t1 * cw1[r] + t2 * cw2[r] +
                     t3 * cw3[r] + t4 * cw4[r];
        f32x4 acc = __builtin_amdgcn_mfma_f32_16x16x32_f16(bf, af, cin, 0, 0, 0);
        float p = 0.f;
#pragma unroll
        for (int r = 0; r < 4; r++) p += fmaxf(acc[r], 0.0f) * vb[r];
        p += __shfl_xor(p, 16);
        p += __shfl_xor(p, 32);
        if (lane < 16) {
            int ee = e0 + w * 64 + q * 16 + lane;
            if (ee < E) __builtin_nontemporal_store(p + b2v, out + ee);
        }
    }
}

// ---------------------------------------------------------------------------
extern "C" void kernel_launch(void* const* d_in, const int* in_sizes, int n_in,
                              void* d_out, int out_size, void* d_ws, size_t ws_size,
                              hipStream_t stream) {
    const int* seq     = (const int*)d_in[0];
    const float* xcov  = (const float*)d_in[1];
    const int* ei      = (const int*)d_in[2];
    const float* eattr = (const float*)d_in[3];
    const int* batch   = (const int*)d_in[4];
    const float* embed = (const float*)d_in[5];
    const float* w1    = (const float*)d_in[6];
    const float* b1    = (const float*)d_in[7];
    const float* w2    = (const float*)d_in[8];
    const float* b2    = (const float*)d_in[9];
    const float* we1   = (const float*)d_in[10];
    const float* be1   = (const float*)d_in[11];
    const float* we2   = (const float*)d_in[12];
    const float* be2   = (const float*)d_in[13];
    float* out         = (float*)d_out;   // fp32 output

    int N = in_sizes[1];
    int E = in_sizes[2] / 2;

    char* ws = (char*)d_ws;
    size_t off_b = 0;
    auto alloc = [&](size_t bytes) -> void* {
        void* p = ws + off_b;
        off_b += (bytes + 255) & ~(size_t)255;
        return p;
    };
    float* M1    = (float*)alloc((size_t)N * 16 * sizeof(float));
    float* M2    = (float*)alloc((size_t)N * 16 * sizeof(float));
    char* Hf     = (char*)alloc((size_t)N * 32);
    int* bndg    = (int*)alloc((NG + 1) * sizeof(int));
    int* gcnt    = (int*)alloc(NG * 16 * sizeof(int));
    int2* glist  = (int2*)alloc((size_t)NG * SEGCAP * sizeof(int2));
    int2* OD     = (int2*)alloc((size_t)N * sizeof(int2));
    float* Dinv  = (float*)alloc((size_t)N * sizeof(float));
    int* csrD    = (int*)alloc((size_t)NG * SEGCAP * sizeof(int));

    int gn = (N + BS - 1) / BS;
    int gp = (E + BS * 4 - 1) / (BS * 4);
    int ge = (E + BS - 1) / BS;

    encode_kernel<<<gn, BS, 0, stream>>>(seq, xcov, batch, embed, w1, b1,
                                         M1, gcnt, bndg, N);
    prep_kernel<<<gp, BS, 0, stream>>>(ei, bndg, glist, gcnt, E);
    csr_kernel<<<NG, BS3, 0, stream>>>(glist, gcnt, bndg, OD, Dinv, csrD);
    layer1_kernel<<<gn, BS, 0, stream>>>(OD, Dinv, csrD, M1, M2, w2, b2, N);
    layer2_kernel<<<gn, BS, 0, stream>>>(OD, Dinv, csrD, M2, Hf, N);
    edge_mlp_kernel<<<ge, BS, 0, stream>>>(ei, Hf, eattr, we1, be1, we2, be2, out, E);
}

// Round 10
// 250.844 us; speedup vs baseline: 1.0782x; 1.0149x over previous
//
#include <hip/hip_runtime.h>
#include <hip/hip_bf16.h>
#include <hip/hip_fp16.h>

#define BS 256
#define BS3 256          // csr kernel block size
#define NG 64            // NUM_GRAPHS (fixed by the problem)
#define NMAX 2048        // max nodes per graph (mean 1563)
#define SEGCAP 4096      // max valid edges per graph (mean ~780)
#define SUBN 16          // sub-buckets per graph (atomic de-contention)
#define SUBCAP 256       // SEGCAP / SUBN; expected fill ~49

typedef _Float16 f16x8 __attribute__((ext_vector_type(8)));
typedef float f32x4 __attribute__((ext_vector_type(4)));

__device__ __forceinline__ uint4 pack8(const float* f) {
    union { uint4 u; __half2 h[4]; } v;
    v.h[0] = __floats2half2_rn(f[0], f[1]);
    v.h[1] = __floats2half2_rn(f[2], f[3]);
    v.h[2] = __floats2half2_rn(f[4], f[5]);
    v.h[3] = __floats2half2_rn(f[6], f[7]);
    return v.u;
}

// ---------------------------------------------------------------------------
// K1: zero gcnt (all 64x16 sub-counters), graph bounds, encode -> M1
// ---------------------------------------------------------------------------
__global__ __launch_bounds__(BS) void encode_kernel(
        const int* __restrict__ seq,
        const float* __restrict__ xcov,
        const int* __restrict__ batch,
        const float* __restrict__ embed,   // 6x16
        const float* __restrict__ w1,      // 17x16
        const float* __restrict__ b1,      // 16
        float* __restrict__ M1,
        int* __restrict__ gcnt,            // 64*16 sub-counters
        int* __restrict__ bnd, int N) {
    __shared__ float sE[96];
    __shared__ float sW1[272];
    __shared__ float sB1[16];
    int tid = threadIdx.x;
    for (int i = tid; i < 96; i += BS) sE[i] = embed[i];
    for (int i = tid; i < 272; i += BS) sW1[i] = w1[i];
    if (tid < 16) sB1[tid] = b1[tid];
    __syncthreads();

    if (blockIdx.x == 0) {
        for (int i = tid; i < NG * 16; i += BS) gcnt[i] = 0;
    }

    int n = blockIdx.x * BS + tid;
    if (n >= N) return;

    int b = batch[n];
    if (n == 0) {
        for (int g = 0; g <= b; g++) bnd[g] = 0;
    } else {
        int pb = batch[n - 1];
        for (int g = pb + 1; g <= b; g++) bnd[g] = n;
    }
    if (n == N - 1) {
        for (int g = b + 1; g <= NG; g++) bnd[g] = N;
    }

    const int4* t4 = (const int4*)(seq + (size_t)n * 64);
    int c1 = 0, c2 = 0, c3 = 0, c4 = 0, c5 = 0;
#pragma unroll
    for (int i = 0; i < 16; i++) {
        int4 v = t4[i];
        c1 += (v.x == 1) + (v.y == 1) + (v.z == 1) + (v.w == 1);
        c2 += (v.x == 2) + (v.y == 2) + (v.z == 2) + (v.w == 2);
        c3 += (v.x == 3) + (v.y == 3) + (v.z == 3) + (v.w == 3);
        c4 += (v.x == 4) + (v.y == 4) + (v.z == 4) + (v.w == 4);
        c5 += (v.x == 5) + (v.y == 5) + (v.z == 5) + (v.w == 5);
    }
    float f1 = (float)c1, f2 = (float)c2, f3 = (float)c3, f4 = (float)c4, f5 = (float)c5;
    float tot = f1 + f2 + f3 + f4 + f5;
    float inv = 1.0f / fmaxf(tot, 1.0f);
    float h[16];
#pragma unroll
    for (int j = 0; j < 16; j++)
        h[j] = (f1 * sE[16 + j] + f2 * sE[32 + j] + f3 * sE[48 + j] +
                f4 * sE[64 + j] + f5 * sE[80 + j]) * inv;
    float xc = xcov[n];
    float o[16];
#pragma unroll
    for (int j = 0; j < 16; j++) o[j] = sB1[j] + xc * sW1[256 + j];
#pragma unroll
    for (int k = 0; k < 16; k++) {
        float hk = h[k];
#pragma unroll
        for (int j = 0; j < 16; j++) o[j] += hk * sW1[k * 16 + j];
    }
    float4* mr = (float4*)(M1 + (size_t)n * 16);
    mr[0] = make_float4(o[0], o[1], o[2], o[3]);
    mr[1] = make_float4(o[4], o[5], o[6], o[7]);
    mr[2] = make_float4(o[8], o[9], o[10], o[11]);
    mr[3] = make_float4(o[12], o[13], o[14], o[15]);
}

// ---------------------------------------------------------------------------
// K2: prep — validity via LDS bound search, bucket valid edges per graph.
// ---------------------------------------------------------------------------
__device__ __forceinline__ int find_graph(const int* bnd, int s) {
    int g = 0;
#pragma unroll
    for (int step = 32; step; step >>= 1) {
        int c = g + step;
        if (c <= NG - 1 && bnd[c] <= s) g = c;
    }
    return g;
}

__global__ __launch_bounds__(BS) void prep_kernel(
        const int* __restrict__ ei,
        const int* __restrict__ bndg,
        int2* __restrict__ glist,
        int* __restrict__ gcnt, int E) {
    __shared__ int sBnd[NG + 1];
    int tid = threadIdx.x;
    if (tid <= NG) sBnd[tid] = bndg[tid];
    __syncthreads();

    int sub = blockIdx.x & (SUBN - 1);
    int idx = (blockIdx.x * BS + tid) * 4;
    if (idx + 3 < E) {
        int4 s4 = *(const int4*)(ei + idx);
        int4 d4 = *(const int4*)(ei + E + idx);
#pragma unroll
        for (int j = 0; j < 4; j++) {
            int s = (&s4.x)[j], d = (&d4.x)[j];
            int g = find_graph(sBnd, s);
            if (d >= sBnd[g] && d < sBnd[g + 1]) {
                int pos = atomicAdd(&gcnt[g * 16 + sub], 1);
                if (pos < SUBCAP)
                    glist[(size_t)g * SEGCAP + sub * SUBCAP + pos] = make_int2(s, d);
            }
        }
    } else {
        for (int j = 0; j < 4; j++) {
            int e = idx + j;
            if (e < E) {
                int s = ei[e], d = ei[E + e];
                int g = find_graph(sBnd, s);
                if (d >= sBnd[g] && d < sBnd[g + 1]) {
                    int pos = atomicAdd(&gcnt[g * 16 + sub], 1);
                    if (pos < SUBCAP)
                        glist[(size_t)g * SEGCAP + sub * SUBCAP + pos] = make_int2(s, d);
                }
            }
        }
    }
}

// ---------------------------------------------------------------------------
// K3a: one block per graph. Counting-sort CSR into GLOBAL arrays.
// ---------------------------------------------------------------------------
__global__ __launch_bounds__(BS3) void csr_kernel(
        const int2* __restrict__ glist,
        const int* __restrict__ gcnt,
        const int* __restrict__ bnd,
        int2* __restrict__ OD,
        float* __restrict__ Dinv,
        int* __restrict__ csrD) {
    __shared__ int hist[NMAX];
    __shared__ int off[NMAX + 1];
    __shared__ int cur[NMAX];
    __shared__ int wsum[4];
    __shared__ int sCnt[SUBN];

    int tid = threadIdx.x;
    int g = blockIdx.x;
    int lo = bnd[g], hi = bnd[g + 1];
    int ng = hi - lo;
    if (ng > NMAX) ng = NMAX;

    for (int i = tid; i < NMAX; i += BS3) hist[i] = 0;
    if (tid < SUBN) {
        int c = gcnt[g * 16 + tid];
        sCnt[tid] = (c > SUBCAP) ? SUBCAP : c;
    }
    __syncthreads();

    if (ng <= 0) return;

    const int2* seg = glist + (size_t)g * SEGCAP;

    for (int idx = tid; idx < SUBN * SUBCAP; idx += BS3) {
        int c = idx >> 8;
        int k = idx & (SUBCAP - 1);
        if (k < sCnt[c]) atomicAdd(&hist[seg[c * SUBCAP + k].x - lo], 1);
    }
    __syncthreads();

    int i0 = tid * 8;
    int lv[8];
    int s = 0;
#pragma unroll
    for (int k = 0; k < 8; k++) { lv[k] = hist[i0 + k]; s += lv[k]; }
    int lane = tid & 63, wv = tid >> 6;
    int x = s;
#pragma unroll
    for (int o = 1; o < 64; o <<= 1) {
        int y = __shfl_up(x, o);
        if (lane >= o) x += y;
    }
    if (lane == 63) wsum[wv] = x;
    __syncthreads();
    if (wv == 0 && lane < 4) {
        int w = wsum[lane];
#pragma unroll
        for (int o = 1; o < 4; o <<= 1) {
            int y = __shfl_up(w, o);
            if (lane >= o) w += y;
        }
        wsum[lane] = w;
    }
    __syncthreads();
    int base = (wv > 0) ? wsum[wv - 1] : 0;
    int excl = base + x - s;
    int run = excl;
#pragma unroll
    for (int k = 0; k < 8; k++) {
        off[i0 + k] = run;
        cur[i0 + k] = run;
        run += lv[k];
    }
    __syncthreads();

    int gbase = g * SEGCAP;
    for (int i = tid; i < ng; i += BS3) {
        int beg = off[i];
        int dg = ((i + 1 < NMAX) ? off[i + 1] : beg) - beg;
        OD[lo + i] = make_int2(gbase + beg, dg);
        float dgf = (float)dg + 1.0f + 1e-8f;
        Dinv[lo + i] = 1.0f / sqrtf(dgf);
    }

    for (int idx = tid; idx < SUBN * SUBCAP; idx += BS3) {
        int c = idx >> 8;
        int k = idx & (SUBCAP - 1);
        if (k < sCnt[c]) {
            int2 e = seg[c * SUBCAP + k];
            int pos = atomicAdd(&cur[e.x - lo], 1);
            csrD[gbase + pos] = e.y;
        }
    }
}

// ---------------------------------------------------------------------------
// K3b: GCN layer 1, node-parallel. M2 <- (relu(dinv*(agg + dinv*M1))) @ w2 + b2
// ---------------------------------------------------------------------------
__global__ __launch_bounds__(BS) void layer1_kernel(
        const int2* __restrict__ OD,
        const float* __restrict__ Dinv,
        const int* __restrict__ csrD,
        const float* __restrict__ M1,
        float* __restrict__ M2,
        const float* __restrict__ w2,      // 16x16
        const float* __restrict__ b2,      // 16
        int N) {
    __shared__ float sW2[256];
    __shared__ float sB2[16];
    int tid = threadIdx.x;
    for (int i = tid; i < 256; i += BS) sW2[i] = w2[i];
    if (tid < 16) sB2[tid] = b2[tid];
    __syncthreads();

    int n = blockIdx.x * BS + tid;
    if (n >= N) return;

    int2 od = OD[n];
    float di = Dinv[n];
    float acc[16];
#pragma unroll
    for (int j = 0; j < 16; j++) acc[j] = 0.f;
    int end = od.x + od.y;
    for (int e = od.x; e < end; e++) {
        int d = csrD[e];
        float dd = Dinv[d];
        const float4* m4 = (const float4*)(M1 + (size_t)d * 16);
        float4 a = m4[0], b = m4[1], c = m4[2], q = m4[3];
        acc[0] += dd * a.x; acc[1] += dd * a.y; acc[2] += dd * a.z; acc[3] += dd * a.w;
        acc[4] += dd * b.x; acc[5] += dd * b.y; acc[6] += dd * b.z; acc[7] += dd * b.w;
        acc[8] += dd * c.x; acc[9] += dd * c.y; acc[10] += dd * c.z; acc[11] += dd * c.w;
        acc[12] += dd * q.x; acc[13] += dd * q.y; acc[14] += dd * q.z; acc[15] += dd * q.w;
    }
    const float4* mr = (const float4*)(M1 + (size_t)n * 16);
    float4 m0 = mr[0], m1 = mr[1], m2 = mr[2], m3 = mr[3];
    float m[16] = {m0.x,m0.y,m0.z,m0.w, m1.x,m1.y,m1.z,m1.w,
                   m2.x,m2.y,m2.z,m2.w, m3.x,m3.y,m3.z,m3.w};
    float h[16];
#pragma unroll
    for (int j = 0; j < 16; j++) h[j] = fmaxf(di * (acc[j] + di * m[j]), 0.0f);
    float o[16];
#pragma unroll
    for (int j = 0; j < 16; j++) o[j] = sB2[j];
#pragma unroll
    for (int k = 0; k < 16; k++) {
        float hk = h[k];
#pragma unroll
        for (int j = 0; j < 16; j++) o[j] += hk * sW2[k * 16 + j];
    }
    float4* wr = (float4*)(M2 + (size_t)n * 16);
    wr[0] = make_float4(o[0], o[1], o[2], o[3]);
    wr[1] = make_float4(o[4], o[5], o[6], o[7]);
    wr[2] = make_float4(o[8], o[9], o[10], o[11]);
    wr[3] = make_float4(o[12], o[13], o[14], o[15]);
}

// ---------------------------------------------------------------------------
// K3c: GCN layer 2, node-parallel. H2 -> Hf (16 x f16 = 32 B/node).
// ---------------------------------------------------------------------------
__global__ __launch_bounds__(BS) void layer2_kernel(
        const int2* __restrict__ OD,
        const float* __restrict__ Dinv,
        const int* __restrict__ csrD,
        const float* __restrict__ M2,
        char* __restrict__ Hf,             // N x 32 B f16 rows
        int N) {
    int tid = threadIdx.x;
    int n = blockIdx.x * BS + tid;
    if (n >= N) return;

    int2 od = OD[n];
    float di = Dinv[n];
    float acc[16];
#pragma unroll
    for (int j = 0; j < 16; j++) acc[j] = 0.f;
    int end = od.x + od.y;
    for (int e = od.x; e < end; e++) {
        int d = csrD[e];
        float dd = Dinv[d];
        const float4* m4 = (const float4*)(M2 + (size_t)d * 16);
        float4 a = m4[0], b = m4[1], c = m4[2], q = m4[3];
        acc[0] += dd * a.x; acc[1] += dd * a.y; acc[2] += dd * a.z; acc[3] += dd * a.w;
        acc[4] += dd * b.x; acc[5] += dd * b.y; acc[6] += dd * b.z; acc[7] += dd * b.w;
        acc[8] += dd * c.x; acc[9] += dd * c.y; acc[10] += dd * c.z; acc[11] += dd * c.w;
        acc[12] += dd * q.x; acc[13] += dd * q.y; acc[14] += dd * q.z; acc[15] += dd * q.w;
    }
    const float4* mr = (const float4*)(M2 + (size_t)n * 16);
    float4 m0 = mr[0], m1 = mr[1], m2 = mr[2], m3 = mr[3];
    float m[16] = {m0.x,m0.y,m0.z,m0.w, m1.x,m1.y,m1.z,m1.w,
                   m2.x,m2.y,m2.z,m2.w, m3.x,m3.y,m3.z,m3.w};
    float h[16];
#pragma unroll
    for (int j = 0; j < 16; j++) h[j] = fmaxf(di * (acc[j] + di * m[j]), 0.0f);
    uint4* pr = (uint4*)(Hf + (size_t)n * 32);
    pr[0] = pack8(h); pr[1] = pack8(h + 8);
}

// ---------------------------------------------------------------------------
// K4: edge MLP via MFMA, swapped operands (C^T layout), tuned:
//  - epilogue constants staged once per block in LDS (broadcast reads),
//    not 28 global loads per thread (R9 regression source);
//  - eattr forwarded lane->lane via __shfl (owning lane holds them in regs);
//    no attr LDS tile (LDS 26.6->21 KB);
//  - REGULAR output stores (L2 write-back merges the 16-lane 64B segments;
//    NT scalar stores caused 1.4x write amplification in R9).
// ---------------------------------------------------------------------------
__global__ __launch_bounds__(BS) void edge_mlp_kernel(
        const int* __restrict__ ei,
        const char* __restrict__ Hf,       // N x 32 B f16 h-rows
        const float* __restrict__ eattr,   // E x 5 f32
        const float* __restrict__ we1,     // 37x16 f32
        const float* __restrict__ be1,     // 16
        const float* __restrict__ we2,     // 16
        const float* __restrict__ be2,     // 1
        float* __restrict__ out, int E) {
    __shared__ __align__(16) char sA[4 * 5120];   // per-wave A: 64 rows x 80B
    __shared__ float sW[128];  // [0:80) we1 rows 32..36 | [80:96) be1 | [96:112) we2 | [112] be2
    int tid = threadIdx.x;
    int w = tid >> 6, lane = tid & 63;

    if (tid < 80) sW[tid] = we1[512 + tid];
    else if (tid < 96) sW[tid] = be1[tid - 80];
    else if (tid < 112) sW[tid] = we2[tid - 96];
    else if (tid == 112) sW[112] = be2[0];

    int e0 = blockIdx.x * BS;
    int e = e0 + tid;
    int ec = e < E ? e : (E - 1);
    int s = __builtin_nontemporal_load(ei + ec);
    int d = __builtin_nontemporal_load(ei + E + ec);
    const float* ea = eattr + (size_t)ec * 5;
    float a0 = __builtin_nontemporal_load(ea + 0);
    float a1 = __builtin_nontemporal_load(ea + 1);
    float a2 = __builtin_nontemporal_load(ea + 2);
    float a3 = __builtin_nontemporal_load(ea + 3);
    float a4 = __builtin_nontemporal_load(ea + 4);

    // h gathers (3.2 MB table, L2-resident)
    const uint4* hsp = (const uint4*)(Hf + (size_t)s * 32);
    uint4 hs0 = hsp[0], hs1 = hsp[1];
    const uint4* hdp = (const uint4*)(Hf + (size_t)d * 32);
    uint4 hd0 = hdp[0], hd1 = hdp[1];

    // Wcat^T fragment (first MFMA operand): lane -> col j=lane&15, k-octet lane>>4
    f16x8 bf;
    {
        const float* wr = we1 + ((lane >> 4) * 8) * 16 + (lane & 15);
#pragma unroll
        for (int i = 0; i < 8; i++) bf[i] = (_Float16)wr[i * 16];
    }

    // stage A row (edge = lane)
    char* A = sA + w * 5120;
    {
        uint4* trow = (uint4*)(A + lane * 80);
        trow[0] = hs0; trow[1] = hs1; trow[2] = hd0; trow[3] = hd1;
    }
    __syncthreads();

    // per-lane epilogue constants from LDS (16-lane groups read same addrs -> broadcast)
    int j0 = (lane >> 4) * 4;
    float ub[4], vb[4], cw0[4], cw1[4], cw2[4], cw3[4], cw4[4];
#pragma unroll
    for (int r = 0; r < 4; r++) {
        ub[r]  = sW[80 + j0 + r];
        vb[r]  = sW[96 + j0 + r];
        cw0[r] = sW[0 * 16 + j0 + r];
        cw1[r] = sW[1 * 16 + j0 + r];
        cw2[r] = sW[2 * 16 + j0 + r];
        cw3[r] = sW[3 * 16 + j0 + r];
        cw4[r] = sW[4 * 16 + j0 + r];
    }
    float b2v = sW[112];

#pragma unroll
    for (int q = 0; q < 4; q++) {
        // A operand: edge rows q*16+(lane&15), k-octet lane>>4
        f16x8 af = *(const f16x8*)(A + (q * 16 + (lane & 15)) * 80 + (lane >> 4) * 16);
        // attrs of that edge live in the same wave: lane q*16+(lane&15)
        int src = q * 16 + (lane & 15);
        float t0 = __shfl(a0, src);
        float t1 = __shfl(a1, src);
        float t2 = __shfl(a2, src);
        float t3 = __shfl(a3, src);
        float t4 = __shfl(a4, src);
        f32x4 cin;
#pragma unroll
        for (int r = 0; r < 4; r++)
            cin[r] = ub[r] + t0 * cw0[r] + t1 * cw1[r] + t2 * cw2[r] +
                     t3 * cw3[r] + t4 * cw4[r];
        f32x4 acc = __builtin_amdgcn_mfma_f32_16x16x32_f16(bf, af, cin, 0, 0, 0);
        float p = 0.f;
#pragma unroll
        for (int r = 0; r < 4; r++) p += fmaxf(acc[r], 0.0f) * vb[r];
        p += __shfl_xor(p, 16);
        p += __shfl_xor(p, 32);
        if (lane < 16) {
            int ee = e0 + w * 64 + q * 16 + lane;
            if (ee < E) out[ee] = p + b2v;   // regular store: L2 merges lines
        }
    }
}

// ---------------------------------------------------------------------------
extern "C" void kernel_launch(void* const* d_in, const int* in_sizes, int n_in,
                              void* d_out, int out_size, void* d_ws, size_t ws_size,
                              hipStream_t stream) {
    const int* seq     = (const int*)d_in[0];
    const float* xcov  = (const float*)d_in[1];
    const int* ei      = (const int*)d_in[2];
    const float* eattr = (const float*)d_in[3];
    const int* batch   = (const int*)d_in[4];
    const float* embed = (const float*)d_in[5];
    const float* w1    = (const float*)d_in[6];
    const float* b1    = (const float*)d_in[7];
    const float* w2    = (const float*)d_in[8];
    const float* b2    = (const float*)d_in[9];
    const float* we1   = (const float*)d_in[10];
    const float* be1   = (const float*)d_in[11];
    const float* we2   = (const float*)d_in[12];
    const float* be2   = (const float*)d_in[13];
    float* out         = (float*)d_out;   // fp32 output

    int N = in_sizes[1];
    int E = in_sizes[2] / 2;

    char* ws = (char*)d_ws;
    size_t off_b = 0;
    auto alloc = [&](size_t bytes) -> void* {
        void* p = ws + off_b;
        off_b += (bytes + 255) & ~(size_t)255;
        return p;
    };
    float* M1    = (float*)alloc((size_t)N * 16 * sizeof(float));
    float* M2    = (float*)alloc((size_t)N * 16 * sizeof(float));
    char* Hf     = (char*)alloc((size_t)N * 32);
    int* bndg    = (int*)alloc((NG + 1) * sizeof(int));
    int* gcnt    = (int*)alloc(NG * 16 * sizeof(int));
    int2* glist  = (int2*)alloc((size_t)NG * SEGCAP * sizeof(int2));
    int2* OD     = (int2*)alloc((size_t)N * sizeof(int2));
    float* Dinv  = (float*)alloc((size_t)N * sizeof(float));
    int* csrD    = (int*)alloc((size_t)NG * SEGCAP * sizeof(int));

    int gn = (N + BS - 1) / BS;
    int gp = (E + BS * 4 - 1) / (BS * 4);
    int ge = (E + BS - 1) / BS;

    encode_kernel<<<gn, BS, 0, stream>>>(seq, xcov, batch, embed, w1, b1,
                                         M1, gcnt, bndg, N);
    prep_kernel<<<gp, BS, 0, stream>>>(ei, bndg, glist, gcnt, E);
    csr_kernel<<<NG, BS3, 0, stream>>>(glist, gcnt, bndg, OD, Dinv, csrD);
    layer1_kernel<<<gn, BS, 0, stream>>>(OD, Dinv, csrD, M1, M2, w2, b2, N);
    layer2_kernel<<<gn, BS, 0, stream>>>(OD, Dinv, csrD, M2, Hf, N);
    edge_mlp_kernel<<<ge, BS, 0, stream>>>(ei, Hf, eattr, we1, be1, we2, be2, out, E);
}

// Round 11
// 246.010 us; speedup vs baseline: 1.0994x; 1.0196x over previous
//
#include <hip/hip_runtime.h>
#include <hip/hip_bf16.h>
#include <hip/hip_fp16.h>

#define BS 256
#define BS3 256          // csr kernel block size
#define NG 64            // NUM_GRAPHS (fixed by the problem)
#define NMAX 2048        // max nodes per graph (mean 1563)
#define SEGCAP 4096      // max valid edges per graph (mean ~780)
#define SUBN 16          // sub-buckets per graph (atomic de-contention)
#define SUBCAP 256       // SEGCAP / SUBN; expected fill ~49

typedef _Float16 f16x8 __attribute__((ext_vector_type(8)));
typedef float f32x4 __attribute__((ext_vector_type(4)));

__device__ __forceinline__ uint4 pack8(const float* f) {
    union { uint4 u; __half2 h[4]; } v;
    v.h[0] = __floats2half2_rn(f[0], f[1]);
    v.h[1] = __floats2half2_rn(f[2], f[3]);
    v.h[2] = __floats2half2_rn(f[4], f[5]);
    v.h[3] = __floats2half2_rn(f[6], f[7]);
    return v.u;
}

// ---------------------------------------------------------------------------
// K1: zero gcnt (all 64x16 sub-counters), graph bounds, encode -> M1
// ---------------------------------------------------------------------------
__global__ __launch_bounds__(BS) void encode_kernel(
        const int* __restrict__ seq,
        const float* __restrict__ xcov,
        const int* __restrict__ batch,
        const float* __restrict__ embed,   // 6x16
        const float* __restrict__ w1,      // 17x16
        const float* __restrict__ b1,      // 16
        float* __restrict__ M1,
        int* __restrict__ gcnt,            // 64*16 sub-counters
        int* __restrict__ bnd, int N) {
    __shared__ float sE[96];
    __shared__ float sW1[272];
    __shared__ float sB1[16];
    int tid = threadIdx.x;
    for (int i = tid; i < 96; i += BS) sE[i] = embed[i];
    for (int i = tid; i < 272; i += BS) sW1[i] = w1[i];
    if (tid < 16) sB1[tid] = b1[tid];
    __syncthreads();

    if (blockIdx.x == 0) {
        for (int i = tid; i < NG * 16; i += BS) gcnt[i] = 0;
    }

    int n = blockIdx.x * BS + tid;
    if (n >= N) return;

    int b = batch[n];
    if (n == 0) {
        for (int g = 0; g <= b; g++) bnd[g] = 0;
    } else {
        int pb = batch[n - 1];
        for (int g = pb + 1; g <= b; g++) bnd[g] = n;
    }
    if (n == N - 1) {
        for (int g = b + 1; g <= NG; g++) bnd[g] = N;
    }

    const int4* t4 = (const int4*)(seq + (size_t)n * 64);
    int c1 = 0, c2 = 0, c3 = 0, c4 = 0, c5 = 0;
#pragma unroll
    for (int i = 0; i < 16; i++) {
        int4 v = t4[i];
        c1 += (v.x == 1) + (v.y == 1) + (v.z == 1) + (v.w == 1);
        c2 += (v.x == 2) + (v.y == 2) + (v.z == 2) + (v.w == 2);
        c3 += (v.x == 3) + (v.y == 3) + (v.z == 3) + (v.w == 3);
        c4 += (v.x == 4) + (v.y == 4) + (v.z == 4) + (v.w == 4);
        c5 += (v.x == 5) + (v.y == 5) + (v.z == 5) + (v.w == 5);
    }
    float f1 = (float)c1, f2 = (float)c2, f3 = (float)c3, f4 = (float)c4, f5 = (float)c5;
    float tot = f1 + f2 + f3 + f4 + f5;
    float inv = 1.0f / fmaxf(tot, 1.0f);
    float h[16];
#pragma unroll
    for (int j = 0; j < 16; j++)
        h[j] = (f1 * sE[16 + j] + f2 * sE[32 + j] + f3 * sE[48 + j] +
                f4 * sE[64 + j] + f5 * sE[80 + j]) * inv;
    float xc = xcov[n];
    float o[16];
#pragma unroll
    for (int j = 0; j < 16; j++) o[j] = sB1[j] + xc * sW1[256 + j];
#pragma unroll
    for (int k = 0; k < 16; k++) {
        float hk = h[k];
#pragma unroll
        for (int j = 0; j < 16; j++) o[j] += hk * sW1[k * 16 + j];
    }
    float4* mr = (float4*)(M1 + (size_t)n * 16);
    mr[0] = make_float4(o[0], o[1], o[2], o[3]);
    mr[1] = make_float4(o[4], o[5], o[6], o[7]);
    mr[2] = make_float4(o[8], o[9], o[10], o[11]);
    mr[3] = make_float4(o[12], o[13], o[14], o[15]);
}

// ---------------------------------------------------------------------------
// K2: prep — validity via LDS bound search, bucket valid edges per graph.
// ---------------------------------------------------------------------------
__device__ __forceinline__ int find_graph(const int* bnd, int s) {
    int g = 0;
#pragma unroll
    for (int step = 32; step; step >>= 1) {
        int c = g + step;
        if (c <= NG - 1 && bnd[c] <= s) g = c;
    }
    return g;
}

__global__ __launch_bounds__(BS) void prep_kernel(
        const int* __restrict__ ei,
        const int* __restrict__ bndg,
        int2* __restrict__ glist,
        int* __restrict__ gcnt, int E) {
    __shared__ int sBnd[NG + 1];
    int tid = threadIdx.x;
    if (tid <= NG) sBnd[tid] = bndg[tid];
    __syncthreads();

    int sub = blockIdx.x & (SUBN - 1);
    int idx = (blockIdx.x * BS + tid) * 4;
    if (idx + 3 < E) {
        int4 s4 = *(const int4*)(ei + idx);
        int4 d4 = *(const int4*)(ei + E + idx);
#pragma unroll
        for (int j = 0; j < 4; j++) {
            int s = (&s4.x)[j], d = (&d4.x)[j];
            int g = find_graph(sBnd, s);
            if (d >= sBnd[g] && d < sBnd[g + 1]) {
                int pos = atomicAdd(&gcnt[g * 16 + sub], 1);
                if (pos < SUBCAP)
                    glist[(size_t)g * SEGCAP + sub * SUBCAP + pos] = make_int2(s, d);
            }
        }
    } else {
        for (int j = 0; j < 4; j++) {
            int e = idx + j;
            if (e < E) {
                int s = ei[e], d = ei[E + e];
                int g = find_graph(sBnd, s);
                if (d >= sBnd[g] && d < sBnd[g + 1]) {
                    int pos = atomicAdd(&gcnt[g * 16 + sub], 1);
                    if (pos < SUBCAP)
                        glist[(size_t)g * SEGCAP + sub * SUBCAP + pos] = make_int2(s, d);
                }
            }
        }
    }
}

// ---------------------------------------------------------------------------
// K3a: one block per graph. Counting-sort CSR into GLOBAL arrays.
// ---------------------------------------------------------------------------
__global__ __launch_bounds__(BS3) void csr_kernel(
        const int2* __restrict__ glist,
        const int* __restrict__ gcnt,
        const int* __restrict__ bnd,
        int2* __restrict__ OD,
        float* __restrict__ Dinv,
        int* __restrict__ csrD) {
    __shared__ int hist[NMAX];
    __shared__ int off[NMAX + 1];
    __shared__ int cur[NMAX];
    __shared__ int wsum[4];
    __shared__ int sCnt[SUBN];

    int tid = threadIdx.x;
    int g = blockIdx.x;
    int lo = bnd[g], hi = bnd[g + 1];
    int ng = hi - lo;
    if (ng > NMAX) ng = NMAX;

    for (int i = tid; i < NMAX; i += BS3) hist[i] = 0;
    if (tid < SUBN) {
        int c = gcnt[g * 16 + tid];
        sCnt[tid] = (c > SUBCAP) ? SUBCAP : c;
    }
    __syncthreads();

    if (ng <= 0) return;

    const int2* seg = glist + (size_t)g * SEGCAP;

    for (int idx = tid; idx < SUBN * SUBCAP; idx += BS3) {
        int c = idx >> 8;
        int k = idx & (SUBCAP - 1);
        if (k < sCnt[c]) atomicAdd(&hist[seg[c * SUBCAP + k].x - lo], 1);
    }
    __syncthreads();

    int i0 = tid * 8;
    int lv[8];
    int s = 0;
#pragma unroll
    for (int k = 0; k < 8; k++) { lv[k] = hist[i0 + k]; s += lv[k]; }
    int lane = tid & 63, wv = tid >> 6;
    int x = s;
#pragma unroll
    for (int o = 1; o < 64; o <<= 1) {
        int y = __shfl_up(x, o);
        if (lane >= o) x += y;
    }
    if (lane == 63) wsum[wv] = x;
    __syncthreads();
    if (wv == 0 && lane < 4) {
        int w = wsum[lane];
#pragma unroll
        for (int o = 1; o < 4; o <<= 1) {
            int y = __shfl_up(w, o);
            if (lane >= o) w += y;
        }
        wsum[lane] = w;
    }
    __syncthreads();
    int base = (wv > 0) ? wsum[wv - 1] : 0;
    int excl = base + x - s;
    int run = excl;
#pragma unroll
    for (int k = 0; k < 8; k++) {
        off[i0 + k] = run;
        cur[i0 + k] = run;
        run += lv[k];
    }
    __syncthreads();

    int gbase = g * SEGCAP;
    for (int i = tid; i < ng; i += BS3) {
        int beg = off[i];
        int dg = ((i + 1 < NMAX) ? off[i + 1] : beg) - beg;
        OD[lo + i] = make_int2(gbase + beg, dg);
        float dgf = (float)dg + 1.0f + 1e-8f;
        Dinv[lo + i] = 1.0f / sqrtf(dgf);
    }

    for (int idx = tid; idx < SUBN * SUBCAP; idx += BS3) {
        int c = idx >> 8;
        int k = idx & (SUBCAP - 1);
        if (k < sCnt[c]) {
            int2 e = seg[c * SUBCAP + k];
            int pos = atomicAdd(&cur[e.x - lo], 1);
            csrD[gbase + pos] = e.y;
        }
    }
}

// ---------------------------------------------------------------------------
// K3b: GCN layer 1, node-parallel. M2 <- (relu(dinv*(agg + dinv*M1))) @ w2 + b2
// ---------------------------------------------------------------------------
__global__ __launch_bounds__(BS) void layer1_kernel(
        const int2* __restrict__ OD,
        const float* __restrict__ Dinv,
        const int* __restrict__ csrD,
        const float* __restrict__ M1,
        float* __restrict__ M2,
        const float* __restrict__ w2,      // 16x16
        const float* __restrict__ b2,      // 16
        int N) {
    __shared__ float sW2[256];
    __shared__ float sB2[16];
    int tid = threadIdx.x;
    for (int i = tid; i < 256; i += BS) sW2[i] = w2[i];
    if (tid < 16) sB2[tid] = b2[tid];
    __syncthreads();

    int n = blockIdx.x * BS + tid;
    if (n >= N) return;

    int2 od = OD[n];
    float di = Dinv[n];
    float acc[16];
#pragma unroll
    for (int j = 0; j < 16; j++) acc[j] = 0.f;
    int end = od.x + od.y;
    for (int e = od.x; e < end; e++) {
        int d = csrD[e];
        float dd = Dinv[d];
        const float4* m4 = (const float4*)(M1 + (size_t)d * 16);
        float4 a = m4[0], b = m4[1], c = m4[2], q = m4[3];
        acc[0] += dd * a.x; acc[1] += dd * a.y; acc[2] += dd * a.z; acc[3] += dd * a.w;
        acc[4] += dd * b.x; acc[5] += dd * b.y; acc[6] += dd * b.z; acc[7] += dd * b.w;
        acc[8] += dd * c.x; acc[9] += dd * c.y; acc[10] += dd * c.z; acc[11] += dd * c.w;
        acc[12] += dd * q.x; acc[13] += dd * q.y; acc[14] += dd * q.z; acc[15] += dd * q.w;
    }
    const float4* mr = (const float4*)(M1 + (size_t)n * 16);
    float4 m0 = mr[0], m1 = mr[1], m2 = mr[2], m3 = mr[3];
    float m[16] = {m0.x,m0.y,m0.z,m0.w, m1.x,m1.y,m1.z,m1.w,
                   m2.x,m2.y,m2.z,m2.w, m3.x,m3.y,m3.z,m3.w};
    float h[16];
#pragma unroll
    for (int j = 0; j < 16; j++) h[j] = fmaxf(di * (acc[j] + di * m[j]), 0.0f);
    float o[16];
#pragma unroll
    for (int j = 0; j < 16; j++) o[j] = sB2[j];
#pragma unroll
    for (int k = 0; k < 16; k++) {
        float hk = h[k];
#pragma unroll
        for (int j = 0; j < 16; j++) o[j] += hk * sW2[k * 16 + j];
    }
    float4* wr = (float4*)(M2 + (size_t)n * 16);
    wr[0] = make_float4(o[0], o[1], o[2], o[3]);
    wr[1] = make_float4(o[4], o[5], o[6], o[7]);
    wr[2] = make_float4(o[8], o[9], o[10], o[11]);
    wr[3] = make_float4(o[12], o[13], o[14], o[15]);
}

// ---------------------------------------------------------------------------
// K3c: GCN layer 2, node-parallel. H2 -> Hf (16 x f16 = 32 B/node).
// ---------------------------------------------------------------------------
__global__ __launch_bounds__(BS) void layer2_kernel(
        const int2* __restrict__ OD,
        const float* __restrict__ Dinv,
        const int* __restrict__ csrD,
        const float* __restrict__ M2,
        char* __restrict__ Hf,             // N x 32 B f16 rows
        int N) {
    int tid = threadIdx.x;
    int n = blockIdx.x * BS + tid;
    if (n >= N) return;

    int2 od = OD[n];
    float di = Dinv[n];
    float acc[16];
#pragma unroll
    for (int j = 0; j < 16; j++) acc[j] = 0.f;
    int end = od.x + od.y;
    for (int e = od.x; e < end; e++) {
        int d = csrD[e];
        float dd = Dinv[d];
        const float4* m4 = (const float4*)(M2 + (size_t)d * 16);
        float4 a = m4[0], b = m4[1], c = m4[2], q = m4[3];
        acc[0] += dd * a.x; acc[1] += dd * a.y; acc[2] += dd * a.z; acc[3] += dd * a.w;
        acc[4] += dd * b.x; acc[5] += dd * b.y; acc[6] += dd * b.z; acc[7] += dd * b.w;
        acc[8] += dd * c.x; acc[9] += dd * c.y; acc[10] += dd * c.z; acc[11] += dd * c.w;
        acc[12] += dd * q.x; acc[13] += dd * q.y; acc[14] += dd * q.z; acc[15] += dd * q.w;
    }
    const float4* mr = (const float4*)(M2 + (size_t)n * 16);
    float4 m0 = mr[0], m1 = mr[1], m2 = mr[2], m3 = mr[3];
    float m[16] = {m0.x,m0.y,m0.z,m0.w, m1.x,m1.y,m1.z,m1.w,
                   m2.x,m2.y,m2.z,m2.w, m3.x,m3.y,m3.z,m3.w};
    float h[16];
#pragma unroll
    for (int j = 0; j < 16; j++) h[j] = fmaxf(di * (acc[j] + di * m[j]), 0.0f);
    uint4* pr = (uint4*)(Hf + (size_t)n * 32);
    pr[0] = pack8(h); pr[1] = pack8(h + 8);
}

// ---------------------------------------------------------------------------
// K4: edge MLP via MFMA (R7-exact, measured 57.2 us). Per wave: 64 edges.
// Gather h_src,h_dst (3.2 MB table, L2-resident), stage [hs|hd] as 64x32 f16
// LDS tile (80-B rows), one mfma_f32_16x16x32_f16 per 16 edges computes
// p+q = [hs|hd] @ we1[0:32]. Transpose C back via LDS, then f32 epilogue.
// ---------------------------------------------------------------------------
__global__ __launch_bounds__(BS) void edge_mlp_kernel(
        const int* __restrict__ ei,
        const char* __restrict__ Hf,       // N x 32 B f16 h-rows
        const float* __restrict__ eattr,   // E x 5 f32
        const float* __restrict__ we1,     // 37x16 f32
        const float* __restrict__ be1,     // 16
        const float* __restrict__ we2,     // 16
        const float* __restrict__ be2,     // 1
        float* __restrict__ out, int E) {
    __shared__ __align__(16) char sT[4 * 5120];   // per-wave 64x80B tile (A, then C)
    __shared__ float sC[80];   // we1 rows 32..36
    __shared__ float sB[16];
    __shared__ float sV[16];
    __shared__ float sb2;
    int tid = threadIdx.x;
    int w = tid >> 6, lane = tid & 63;
    if (tid < 80) sC[tid] = we1[512 + tid];
    if (tid < 16) { sB[tid] = be1[tid]; sV[tid] = we2[tid]; }
    if (tid == 0) sb2 = be2[0];

    int e = blockIdx.x * BS + tid;
    int ec = e < E ? e : (E - 1);
    int s = __builtin_nontemporal_load(ei + ec);
    int d = __builtin_nontemporal_load(ei + E + ec);
    const float* ea = eattr + (size_t)ec * 5;
    float a0 = __builtin_nontemporal_load(ea + 0);
    float a1 = __builtin_nontemporal_load(ea + 1);
    float a2 = __builtin_nontemporal_load(ea + 2);
    float a3 = __builtin_nontemporal_load(ea + 3);
    float a4 = __builtin_nontemporal_load(ea + 4);

    // h gathers: plain loads (want L2 retention; table is L2-resident)
    const uint4* hsp = (const uint4*)(Hf + (size_t)s * 32);
    uint4 hs0 = hsp[0], hs1 = hsp[1];
    const uint4* hdp = (const uint4*)(Hf + (size_t)d * 32);
    uint4 hd0 = hdp[0], hd1 = hdp[1];

    // B fragment: Wcat[k][j] = we1[k*16+j], k=(lane>>4)*8+i, j=lane&15
    f16x8 bf;
    {
        const float* wr = we1 + ((lane >> 4) * 8) * 16 + (lane & 15);
#pragma unroll
        for (int i = 0; i < 8; i++) bf[i] = (_Float16)wr[i * 16];
    }

    char* T = sT + w * 5120;
    // A-tile write: row = lane (edge), 32 f16 = [hs(16) | hd(16)], 80-B rows
    {
        uint4* trow = (uint4*)(T + lane * 80);
        trow[0] = hs0; trow[1] = hs1; trow[2] = hd0; trow[3] = hd1;
    }
    __syncthreads();

    // 4 quarters: read A-frag (16 rows x K=32), MFMA, scatter C into same rows
    // (safe: wave issues the quarter's A-reads before its C-writes; DS pipe
    //  is in-order per wave; later quarters touch disjoint rows).
#pragma unroll
    for (int q = 0; q < 4; q++) {
        f16x8 af = *(const f16x8*)(T + (q * 16 + (lane & 15)) * 80 + (lane >> 4) * 16);
        f32x4 z = {0.f, 0.f, 0.f, 0.f};
        f32x4 c = __builtin_amdgcn_mfma_f32_16x16x32_f16(af, bf, z, 0, 0, 0);
        int rbase = q * 16 + (lane >> 4) * 4;
#pragma unroll
        for (int r = 0; r < 4; r++)
            *(float*)(T + (rbase + r) * 80 + (lane & 15) * 4) = c[r];
    }
    __syncthreads();

    // read back my edge's p+q row (16 f32)
    float4 p0 = *(const float4*)(T + lane * 80 + 0);
    float4 p1 = *(const float4*)(T + lane * 80 + 16);
    float4 p2 = *(const float4*)(T + lane * 80 + 32);
    float4 p3 = *(const float4*)(T + lane * 80 + 48);
    float ppq[16] = {p0.x,p0.y,p0.z,p0.w, p1.x,p1.y,p1.z,p1.w,
                     p2.x,p2.y,p2.z,p2.w, p3.x,p3.y,p3.z,p3.w};

    float lg = sb2;
#pragma unroll
    for (int j = 0; j < 16; j++) {
        float acc = sB[j] + ppq[j] +
                    a0 * sC[j] + a1 * sC[16 + j] + a2 * sC[32 + j] +
                    a3 * sC[48 + j] + a4 * sC[64 + j];
        lg += fmaxf(acc, 0.0f) * sV[j];
    }
    if (e < E) __builtin_nontemporal_store(lg, out + e);
}

// ---------------------------------------------------------------------------
extern "C" void kernel_launch(void* const* d_in, const int* in_sizes, int n_in,
                              void* d_out, int out_size, void* d_ws, size_t ws_size,
                              hipStream_t stream) {
    const int* seq     = (const int*)d_in[0];
    const float* xcov  = (const float*)d_in[1];
    const int* ei      = (const int*)d_in[2];
    const float* eattr = (const float*)d_in[3];
    const int* batch   = (const int*)d_in[4];
    const float* embed = (const float*)d_in[5];
    const float* w1    = (const float*)d_in[6];
    const float* b1    = (const float*)d_in[7];
    const float* w2    = (const float*)d_in[8];
    const float* b2    = (const float*)d_in[9];
    const float* we1   = (const float*)d_in[10];
    const float* be1   = (const float*)d_in[11];
    const float* we2   = (const float*)d_in[12];
    const float* be2   = (const float*)d_in[13];
    float* out         = (float*)d_out;   // fp32 output

    int N = in_sizes[1];
    int E = in_sizes[2] / 2;

    char* ws = (char*)d_ws;
    size_t off_b = 0;
    auto alloc = [&](size_t bytes) -> void* {
        void* p = ws + off_b;
        off_b += (bytes + 255) & ~(size_t)255;
        return p;
    };
    float* M1    = (float*)alloc((size_t)N * 16 * sizeof(float));
    float* M2    = (float*)alloc((size_t)N * 16 * sizeof(float));
    char* Hf     = (char*)alloc((size_t)N * 32);
    int* bndg    = (int*)alloc((NG + 1) * sizeof(int));
    int* gcnt    = (int*)alloc(NG * 16 * sizeof(int));
    int2* glist  = (int2*)alloc((size_t)NG * SEGCAP * sizeof(int2));
    int2* OD     = (int2*)alloc((size_t)N * sizeof(int2));
    float* Dinv  = (float*)alloc((size_t)N * sizeof(float));
    int* csrD    = (int*)alloc((size_t)NG * SEGCAP * sizeof(int));

    int gn = (N + BS - 1) / BS;
    int gp = (E + BS * 4 - 1) / (BS * 4);
    int ge = (E + BS - 1) / BS;

    encode_kernel<<<gn, BS, 0, stream>>>(seq, xcov, batch, embed, w1, b1,
                                         M1, gcnt, bndg, N);
    prep_kernel<<<gp, BS, 0, stream>>>(ei, bndg, glist, gcnt, E);
    csr_kernel<<<NG, BS3, 0, stream>>>(glist, gcnt, bndg, OD, Dinv, csrD);
    layer1_kernel<<<gn, BS, 0, stream>>>(OD, Dinv, csrD, M1, M2, w2, b2, N);
    layer2_kernel<<<gn, BS, 0, stream>>>(OD, Dinv, csrD, M2, Hf, N);
    edge_mlp_kernel<<<ge, BS, 0, stream>>>(ei, Hf, eattr, we1, be1, we2, be2, out, E);
}